// Round 8
// baseline (422.839 us; speedup 1.0000x reference)
//
#include <hip/hip_runtime.h>

#define NNODES 8000
#define MPAD   8192          // 32 * 256 (for the 256x256 GEMM1 tile)
#define NEDGES 40000
#define ETOT   (NEDGES + NNODES)   // 48000 with self loops
#define DIN    1024
#define NH     3
#define CH     1024
#define HC     (NH * CH)           // 3072
#define NTOT   (2 * HC)            // 6144 fused xl||xr
#define NCLS   460
#define NCLS_P 512
#define NEG    0.2f

typedef _Float16 h8 __attribute__((ext_vector_type(8)));
typedef _Float16 h4v __attribute__((ext_vector_type(4)));
typedef float    f4 __attribute__((ext_vector_type(4)));

// async global->LDS, 16B per lane; dest = wave-uniform base + lane*16 (m104)
#define GLOAD16(g, l) \
    __builtin_amdgcn_global_load_lds((const __attribute__((address_space(1))) void*)(g), \
                                     (__attribute__((address_space(3))) void*)(l), 16, 0, 0)

// ---------- fp32 -> fp16 convert with row padding ----------
__global__ __launch_bounds__(256)
void fp16_pad_convert(const float* __restrict__ in, _Float16* __restrict__ out,
                      int rows_in, int rows_out, int cols)
{
    size_t i4 = (size_t)blockIdx.x * 256 + threadIdx.x;
    size_t tot = ((size_t)rows_out * cols) >> 2;
    if (i4 >= tot) return;
    size_t e = i4 << 2;
    int row = (int)(e / cols);
    float vx = 0.f, vy = 0.f, vz = 0.f, vw = 0.f;
    if (row < rows_in) {
        float4 v = *(const float4*)(in + e);
        vx = v.x; vy = v.y; vz = v.z; vw = v.w;
    }
    h4v o = { (_Float16)vx, (_Float16)vy, (_Float16)vz, (_Float16)vw };
    *(h4v*)(out + e) = o;
}

// ---------- W[K][Ncols] fp32 -> Wt[rowOff+n][K] fp16 (zero for n >= Ncols) ----------
__global__ __launch_bounds__(256)
void transpose_to_fp16(const float* __restrict__ W, _Float16* __restrict__ Wt,
                       int K, int Ncols, int rowOff)
{
    __shared__ float tile[32][33];
    int n0 = blockIdx.x * 32, k0 = blockIdx.y * 32;
    int tx = threadIdx.x, ty = threadIdx.y;   // block (32,8)
    #pragma unroll
    for (int i = 0; i < 4; ++i) {
        int k = k0 + ty + i * 8;
        int n = n0 + tx;
        tile[ty + i * 8][tx] = (n < Ncols) ? W[(size_t)k * Ncols + n] : 0.f;
    }
    __syncthreads();
    #pragma unroll
    for (int i = 0; i < 4; ++i) {
        int n = n0 + ty + i * 8;
        int k = k0 + tx;
        Wt[(size_t)(rowOff + n) * K + k] = (_Float16)tile[tx][ty + i * 8];
    }
}

// ---------- pack biases + att->fp16 ----------
__global__ __launch_bounds__(256)
void bias_pack(const float* __restrict__ bl, const float* __restrict__ br,
               const float* __restrict__ bf, const float* __restrict__ att,
               float* __restrict__ b1, float* __restrict__ b2, _Float16* __restrict__ atth)
{
    int i = blockIdx.x * 256 + threadIdx.x;
    if (i < HC) { b1[i] = bl[i]; b1[HC + i] = br[i]; atth[i] = (_Float16)att[i]; }
    if (i < NCLS_P) b2[i] = (i < NCLS) ? bf[i] : 0.f;
}

// ---------- CSR build ----------
__global__ __launch_bounds__(256)
void csr_count(const int* __restrict__ ei, int* __restrict__ cnt)
{
    int e = blockIdx.x * 256 + threadIdx.x;
    if (e >= ETOT) return;
    int dst = (e < NEDGES) ? ei[2 * e + 1] : (e - NEDGES);
    atomicAdd(&cnt[dst], 1);
}

__global__ __launch_bounds__(1024)
void csr_scan(const int* __restrict__ cnt, int* __restrict__ rofs)
{
    __shared__ int s[1024];
    int t = threadIdx.x;
    int base = t * 8;
    int local[8];
    int sum = 0;
    #pragma unroll
    for (int i = 0; i < 8; ++i) {
        local[i] = sum;
        sum += (base + i < NNODES) ? cnt[base + i] : 0;
    }
    s[t] = sum;
    __syncthreads();
    for (int off = 1; off < 1024; off <<= 1) {
        int v = (t >= off) ? s[t - off] : 0;
        __syncthreads();
        if (t >= off) s[t] += v;
        __syncthreads();
    }
    int pre = (t > 0) ? s[t - 1] : 0;
    #pragma unroll
    for (int i = 0; i < 8; ++i)
        if (base + i < NNODES) rofs[base + i] = pre + local[i];
}

__global__ __launch_bounds__(256)
void csr_fill(const int* __restrict__ ei, const int* __restrict__ rofs,
              int* __restrict__ cursor, int* __restrict__ csr_src)
{
    int e = blockIdx.x * 256 + threadIdx.x;
    if (e >= ETOT) return;
    int src, dst;
    if (e < NEDGES) { src = ei[2 * e]; dst = ei[2 * e + 1]; }
    else            { src = dst = e - NEDGES; }
    int pos = rofs[dst] + atomicAdd(&cursor[dst], 1);
    csr_src[pos] = src;
}

// ---------- 256x256 8-phase fp16 MFMA GEMM (T3+T4+T5; no T2 swizzle yet) ----------
// C16[M][N] = A[M][K] * Bt[N][K]^T + biasN.  512 thr = 8 waves (2M x 4N),
// BK=64, 128 KiB LDS dbuf; one 16KB half-tile staged per phase (2 gloads/thr);
// vmcnt(4) only at end of p3/p7 (counted, never 0 in loop); raw s_barrier.
__global__ __launch_bounds__(512, 2)
void gemm256_f16(const _Float16* __restrict__ A, const _Float16* __restrict__ Bt,
                 const float* __restrict__ biasN, _Float16* __restrict__ C16,
                 int N, int K)
{
    __shared__ __align__(16) _Float16 lds[65536];   // [buf]{A[256][64] | B[256][64]}

    // XCD swizzle (nwg % 8 == 0)
    int nwg = gridDim.x;
    int orig = blockIdx.x;
    int cpx = nwg >> 3;
    int wg = (orig & 7) * cpx + (orig >> 3);
    int nbx = N >> 8;
    int bm = wg / nbx, bn = wg - bm * nbx;
    int m0 = bm << 8, n0 = bn << 8;

    const int t = threadIdx.x;
    const int lane = t & 63;
    const int w = t >> 6;          // wave 0..7
    const int wm = w >> 2;         // 0..1  (M half)
    const int wn = w & 3;          // 0..3  (N quarter)

    // staging address pieces: each gload = 1KB segment = 8 rows x 64 fp16
    const int sRow = lane >> 3;          // row within segment
    const int sCol = (lane & 7) << 3;    // fp16 col
    const int seg0 = w << 1;             // wave's first segment of 16

    const int l15 = lane & 15;
    const int kl8 = (lane >> 4) << 3;    // 0,8,16,24

    f4 acc[8][4];
    f4 zero = { 0.f, 0.f, 0.f, 0.f };
    #pragma unroll
    for (int i = 0; i < 8; ++i)
        #pragma unroll
        for (int j = 0; j < 4; ++j) acc[i][j] = zero;

    auto STAGE_A = [&](int kt, int h, int b) {
        const _Float16* src = A + (size_t)(m0 + h * 128 + seg0 * 8 + sRow) * K + kt * 64 + sCol;
        int dst = b * 32768 + h * 8192 + seg0 * 512;
        GLOAD16(src, &lds[dst]);
        GLOAD16(src + (size_t)8 * K, &lds[dst + 512]);
    };
    auto STAGE_B = [&](int kt, int h, int b) {
        const _Float16* src = Bt + (size_t)(n0 + h * 128 + seg0 * 8 + sRow) * K + kt * 64 + sCol;
        int dst = b * 32768 + 16384 + h * 8192 + seg0 * 512;
        GLOAD16(src, &lds[dst]);
        GLOAD16(src + (size_t)8 * K, &lds[dst + 512]);
    };

    h8 bfr[4][2];
    const int aBase = wm * 128 + l15;
    const int bBase = wn * 64 + l15;

#define DS_A(fi, ks2, q, b) (*(const h8*)&lds[(b)*32768 + (aBase + (q)*32 + (fi)*16)*64 + (ks2)*32 + kl8])
#define DS_B(nf, ks2, b)    (*(const h8*)&lds[(b)*32768 + 16384 + (bBase + (nf)*16)*64 + (ks2)*32 + kl8])

#define PHASE(b, q, STAGE_STMT, VMEND)                                                            \
    {                                                                                             \
        h8 a00 = DS_A(0, 0, q, b), a01 = DS_A(0, 1, q, b);                                        \
        h8 a10 = DS_A(1, 0, q, b), a11 = DS_A(1, 1, q, b);                                        \
        if ((q) == 0) {                                                                           \
            _Pragma("unroll")                                                                     \
            for (int nf = 0; nf < 4; ++nf) {                                                      \
                bfr[nf][0] = DS_B(nf, 0, b);                                                      \
                bfr[nf][1] = DS_B(nf, 1, b);                                                      \
            }                                                                                     \
        }                                                                                         \
        STAGE_STMT;                                                                               \
        __builtin_amdgcn_s_barrier();                                                             \
        asm volatile("s_waitcnt lgkmcnt(0)" ::: "memory");                                        \
        __builtin_amdgcn_sched_barrier(0);                                                        \
        __builtin_amdgcn_s_setprio(1);                                                            \
        _Pragma("unroll")                                                                         \
        for (int nf = 0; nf < 4; ++nf) {                                                          \
            acc[(q)*2+0][nf] = __builtin_amdgcn_mfma_f32_16x16x32_f16(a00, bfr[nf][0], acc[(q)*2+0][nf], 0, 0, 0); \
            acc[(q)*2+0][nf] = __builtin_amdgcn_mfma_f32_16x16x32_f16(a01, bfr[nf][1], acc[(q)*2+0][nf], 0, 0, 0); \
            acc[(q)*2+1][nf] = __builtin_amdgcn_mfma_f32_16x16x32_f16(a10, bfr[nf][0], acc[(q)*2+1][nf], 0, 0, 0); \
            acc[(q)*2+1][nf] = __builtin_amdgcn_mfma_f32_16x16x32_f16(a11, bfr[nf][1], acc[(q)*2+1][nf], 0, 0, 0); \
        }                                                                                         \
        __builtin_amdgcn_s_setprio(0);                                                            \
        if (VMEND) asm volatile("s_waitcnt vmcnt(4)" ::: "memory");                               \
        __builtin_amdgcn_s_barrier();                                                             \
    }

    // prologue: kt0 fully + kt1's B halves (A(kt1) staged at p0/p1 of iter 0)
    STAGE_A(0, 0, 0); STAGE_A(0, 1, 0);
    STAGE_B(0, 0, 0); STAGE_B(0, 1, 0);
    STAGE_B(1, 0, 1); STAGE_B(1, 1, 1);
    asm volatile("s_waitcnt vmcnt(4)" ::: "memory");   // kt0's 8 loads landed
    __builtin_amdgcn_s_barrier();

    const int NKT = K >> 6;    // 16 K-tiles
    for (int kt = 0; kt < NKT; kt += 2) {
        // phases 0-3: compute kt (buf0)
        PHASE(0, 0, STAGE_A(kt + 1, 0, 1), false);
        PHASE(0, 1, STAGE_A(kt + 1, 1, 1), false);
        PHASE(0, 2, STAGE_B(kt + 2, 0, 0), false);
        PHASE(0, 3, STAGE_B(kt + 2, 1, 0), true);    // vmcnt(4): A(kt+1) landed
        // phases 4-7: compute kt+1 (buf1)
        PHASE(1, 0, STAGE_A(kt + 2, 0, 0), false);
        PHASE(1, 1, STAGE_A(kt + 2, 1, 0), false);
        PHASE(1, 2, STAGE_B(kt + 3, 0, 1), false);
        PHASE(1, 3, STAGE_B(kt + 3, 1, 1), true);    // vmcnt(4): A/B(kt+2) landed
    }
    // (stages past NKT read harmless in-workspace bytes into dead buffers)

#undef PHASE
#undef DS_A
#undef DS_B

    // epilogue: C/D layout col=lane&15, row=(lane>>4)*4+reg (m89-verified)
    #pragma unroll
    for (int mf = 0; mf < 8; ++mf) {
        int row0 = m0 + wm * 128 + mf * 16 + ((lane >> 4) << 2);
        #pragma unroll
        for (int nf = 0; nf < 4; ++nf) {
            int col = n0 + wn * 64 + nf * 16 + l15;
            float bb = biasN[col];
            #pragma unroll
            for (int rg = 0; rg < 4; ++rg)
                C16[(size_t)(row0 + rg) * N + col] = (_Float16)(acc[mf][nf][rg] + bb);
        }
    }
}

// ---------- 128x128 fp16 MFMA GEMM (kept for GEMM2's narrow N) ----------
__global__ __launch_bounds__(256, 4)
void gemm_f16(const _Float16* __restrict__ A, const _Float16* __restrict__ Bt,
              const float* __restrict__ biasN,
              float* __restrict__ C32, _Float16* __restrict__ C16,
              int N, int K)
{
    __shared__ __align__(16) _Float16 sA[128 * 32];
    __shared__ __align__(16) _Float16 sB[128 * 32];

    int nwg = gridDim.x;
    int orig = blockIdx.x;
    int q = nwg >> 3, r = nwg & 7;
    int xcd = orig & 7, idx = orig >> 3;
    int wg = (xcd < r ? xcd * (q + 1) : r * (q + 1) + (xcd - r) * q) + idx;
    int nbx = N >> 7;
    int bm = wg / nbx, bn = wg - bm * nbx;
    int m0 = bm << 7, n0 = bn << 7;

    const int t = threadIdx.x;
    const int lane = t & 63, w = t >> 6;
    const int wr = (w >> 1) << 6, wc = (w & 1) << 6;

    f4 acc[4][4];
    f4 zero = { 0.f, 0.f, 0.f, 0.f };
    #pragma unroll
    for (int i = 0; i < 4; ++i)
        #pragma unroll
        for (int j = 0; j < 4; ++j) acc[i][j] = zero;

    const int lr = lane >> 2, lk = lane & 3;
    const _Float16* gA = A  + (size_t)(m0 + w * 16 + lr) * K + lk * 8;
    const _Float16* gB = Bt + (size_t)(n0 + w * 16 + lr) * K + lk * 8;
    _Float16* lA0 = &sA[w * 512];
    _Float16* lA1 = &sA[2048 + w * 512];
    _Float16* lB0 = &sB[w * 512];
    _Float16* lB1 = &sB[2048 + w * 512];
    const size_t seg = (size_t)64 * K;

    const int nk = K >> 5;
    for (int s = 0; s < nk; ++s) {
        const int ko = s << 5;
        GLOAD16(gA + ko,       lA0);
        GLOAD16(gA + seg + ko, lA1);
        GLOAD16(gB + ko,       lB0);
        GLOAD16(gB + seg + ko, lB1);
        __syncthreads();
        const int ks = lane >> 4;
        h8 bh[4];
        #pragma unroll
        for (int nj = 0; nj < 4; ++nj)
            bh[nj] = *(const h8*)&sB[(wc + nj * 16 + (lane & 15)) * 32 + ks * 8];
        #pragma unroll
        for (int mi = 0; mi < 4; ++mi) {
            h8 ah = *(const h8*)&sA[(wr + mi * 16 + (lane & 15)) * 32 + ks * 8];
            #pragma unroll
            for (int nj = 0; nj < 4; ++nj)
                acc[mi][nj] = __builtin_amdgcn_mfma_f32_16x16x32_f16(ah, bh[nj], acc[mi][nj], 0, 0, 0);
        }
        __syncthreads();
    }

    #pragma unroll
    for (int mi = 0; mi < 4; ++mi) {
        #pragma unroll
        for (int nj = 0; nj < 4; ++nj) {
            int col  = n0 + wc + nj * 16 + (lane & 15);
            int rowb = m0 + wr + mi * 16 + ((lane >> 4) << 2);
            float b = biasN[col];
            #pragma unroll
            for (int rg = 0; rg < 4; ++rg) {
                float v = acc[mi][nj][rg] + b;
                size_t off = (size_t)(rowb + rg) * N + col;
                if (C32) C32[off] = v;
                else     C16[off] = (_Float16)v;
            }
        }
    }
}

// ---------- fused edge path: ONE WAVE per dst, barrier-free (unchanged) ----------
__global__ __launch_bounds__(256)
void edge_fused(const _Float16* __restrict__ xlr, const int* __restrict__ rofs,
                const int* __restrict__ cnt, const int* __restrict__ csr_src,
                const _Float16* __restrict__ atth, const float* __restrict__ bias,
                _Float16* __restrict__ o2h)
{
    const int wid = threadIdx.x >> 6;
    const int dst = (blockIdx.x << 2) + wid;
    const int l   = threadIdx.x & 63;
    const int cb0 = l << 3, cb1 = 512 + (l << 3);

    h8 xr[3][2], at[3][2];
    #pragma unroll
    for (int h = 0; h < 3; ++h) {
        const _Float16* pr = xlr + (size_t)dst * NTOT + HC + h * CH;
        xr[h][0] = *(const h8*)(pr + cb0);
        xr[h][1] = *(const h8*)(pr + cb1);
        at[h][0] = *(const h8*)(atth + h * CH + cb0);
        at[h][1] = *(const h8*)(atth + h * CH + cb1);
    }

    const int beg = rofs[dst];
    const int num = cnt[dst];

    float m[3] = { -3.4e38f, -3.4e38f, -3.4e38f };
    float d[3] = { 0.f, 0.f, 0.f };
    float acc[3][2][8] = {};

    for (int i = 0; i < num; ++i) {
        int src = csr_src[beg + i];
        const _Float16* ps = xlr + (size_t)src * NTOT;
        h8 xv[3][2];
        #pragma unroll
        for (int h = 0; h < 3; ++h) {
            xv[h][0] = *(const h8*)(ps + h * CH + cb0);
            xv[h][1] = *(const h8*)(ps + h * CH + cb1);
        }
        #pragma unroll
        for (int h = 0; h < 3; ++h) {
            float s = 0.f;
            #pragma unroll
            for (int b = 0; b < 2; ++b)
                #pragma unroll
                for (int j = 0; j < 8; ++j) {
                    float z = (float)xv[h][b][j] + (float)xr[h][b][j];
                    z = z > 0.f ? z : NEG * z;
                    s = fmaf((float)at[h][b][j], z, s);
                }
            #pragma unroll
            for (int off = 32; off > 0; off >>= 1) s += __shfl_xor(s, off);
            float nm = fmaxf(m[h], s);
            float rs = __expf(m[h] - nm);
            float wt = __expf(s - nm);
            d[h] = d[h] * rs + wt;
            #pragma unroll
            for (int b = 0; b < 2; ++b)
                #pragma unroll
                for (int j = 0; j < 8; ++j)
                    acc[h][b][j] = fmaf(wt, (float)xv[h][b][j], acc[h][b][j] * rs);
            m[h] = nm;
        }
    }

    float inv0 = 1.f / (d[0] + 1e-16f) * (1.f / 3.f);
    float inv1 = 1.f / (d[1] + 1e-16f) * (1.f / 3.f);
    float inv2 = 1.f / (d[2] + 1e-16f) * (1.f / 3.f);
    #pragma unroll
    for (int b = 0; b < 2; ++b) {
        int c = b ? cb1 : cb0;
        h8 o;
        #pragma unroll
        for (int j = 0; j < 8; ++j) {
            float v = acc[0][b][j] * inv0 + acc[1][b][j] * inv1 + acc[2][b][j] * inv2
                    + bias[c + j];
            o[j] = (_Float16)v;
        }
        *(h8*)(o2h + (size_t)dst * CH + c) = o;
    }
}

// ---------- row softmax over 460 classes, ld 512 ----------
__global__ __launch_bounds__(64)
void row_softmax(const float* __restrict__ logits, float* __restrict__ out)
{
    const int r = blockIdx.x;
    const int lane = threadIdx.x;
    const float* row = logits + (size_t)r * NCLS_P;
    float v[8];
    float mx = -3.4e38f;
    #pragma unroll
    for (int i = 0; i < 8; ++i) {
        int c = lane + i * 64;
        v[i] = (c < NCLS) ? row[c] : -3.4e38f;
        mx = fmaxf(mx, v[i]);
    }
    #pragma unroll
    for (int off = 32; off > 0; off >>= 1) mx = fmaxf(mx, __shfl_xor(mx, off));
    float s = 0.f;
    #pragma unroll
    for (int i = 0; i < 8; ++i) {
        int c = lane + i * 64;
        float ev = (c < NCLS) ? expf(v[i] - mx) : 0.f;
        v[i] = ev;
        s += ev;
    }
    #pragma unroll
    for (int off = 32; off > 0; off >>= 1) s += __shfl_xor(s, off);
    float inv = 1.f / s;
    #pragma unroll
    for (int i = 0; i < 8; ++i) {
        int c = lane + i * 64;
        if (c < NCLS) out[(size_t)r * NCLS + c] = v[i] * inv;
    }
}

extern "C" void kernel_launch(void* const* d_in, const int* in_sizes, int n_in,
                              void* d_out, int out_size, void* d_ws, size_t ws_size,
                              hipStream_t stream)
{
    (void)in_sizes; (void)n_in; (void)out_size; (void)ws_size;

    const float* x    = (const float*)d_in[0];
    const int*   ei   = (const int*)  d_in[1];
    const float* Wl   = (const float*)d_in[2];
    const float* bl   = (const float*)d_in[3];
    const float* Wr   = (const float*)d_in[4];
    const float* br   = (const float*)d_in[5];
    const float* att  = (const float*)d_in[6];
    const float* bias = (const float*)d_in[7];
    const float* Wf   = (const float*)d_in[8];
    const float* bf   = (const float*)d_in[9];

    char* base = (char*)d_ws;
    _Float16* xh      = (_Float16*)(base);                      // [8192][1024]   16,777,216
    _Float16* BtW     = (_Float16*)(base + 16777216);           // [6144][1024]   12,582,912
    _Float16* Wft     = (_Float16*)(base + 29360128);           // [512][1024]     1,048,576
    float*    biasC1  = (float*)   (base + 30408704);           // [6144]             24,576
    float*    biasC2  = (float*)   (base + 30433280);           // [512]               2,048
    _Float16* atth    = (_Float16*)(base + 30435328);           // [3072]              6,144
    int*      cnt     = (int*)     (base + 30441472);           // [8000]             32,000
    int*      cursor  = (int*)     (base + 30473472);           // [8000]             32,000
    int*      rofs    = (int*)     (base + 30505472);           // [8000]             32,000
    int*      csr_src = (int*)     (base + 30537472);           // [48000]           192,000
    _Float16* o2h     = (_Float16*)(base + 30729472);           // [8192][1024]   16,777,216
    float*    logits  = (float*)   (base + 47506688);           // [8192][512]    16,777,216
    _Float16* xlr     = (_Float16*)(base + 64283904);           // [8192][6144]  100,663,296

    // zero cnt | cursor (contiguous) and o2h pad rows (8000..8191)
    hipMemsetAsync(cnt, 0, 64000, stream);
    hipMemsetAsync(o2h + (size_t)NNODES * CH, 0, (size_t)(MPAD - NNODES) * CH * 2, stream);

    fp16_pad_convert<<<(MPAD * DIN / 4 + 255) / 256, 256, 0, stream>>>(
        x, xh, NNODES, MPAD, DIN);

    transpose_to_fp16<<<dim3(HC / 32, DIN / 32), dim3(32, 8), 0, stream>>>(Wl, BtW, DIN, HC, 0);
    transpose_to_fp16<<<dim3(HC / 32, DIN / 32), dim3(32, 8), 0, stream>>>(Wr, BtW, DIN, HC, HC);
    transpose_to_fp16<<<dim3(NCLS_P / 32, DIN / 32), dim3(32, 8), 0, stream>>>(Wf, Wft, DIN, NCLS, 0);

    bias_pack<<<(HC + 255) / 256, 256, 0, stream>>>(bl, br, bf, att, biasC1, biasC2, atth);

    // CSR build (src lists per dst, self-loops included)
    csr_count<<<(ETOT + 255) / 256, 256, 0, stream>>>(ei, cnt);
    csr_scan<<<1, 1024, 0, stream>>>(cnt, rofs);
    csr_fill<<<(ETOT + 255) / 256, 256, 0, stream>>>(ei, rofs, cursor, csr_src);

    // GEMM1 fused (256^2 8-phase): xlr[8192][6144] fp16
    gemm256_f16<<<(MPAD / 256) * (NTOT / 256), 512, 0, stream>>>(
        xh, BtW, biasC1, xlr, NTOT, DIN);

    // fused edge path: wave-per-dst online softmax + weighted gather + bias
    edge_fused<<<NNODES / 4, 256, 0, stream>>>(xlr, rofs, cnt, csr_src, atth, bias, o2h);

    // GEMM2: logits[8192][512] fp32
    gemm_f16<<<(NCLS_P / 128) * (MPAD / 128), 256, 0, stream>>>(
        o2h, Wft, biasC2, logits, nullptr, NCLS_P, DIN);

    row_softmax<<<NNODES, 64, 0, stream>>>(logits, (float*)d_out);
}

// Round 9
// 351.295 us; speedup vs baseline: 1.2037x; 1.2037x over previous
//
#include <hip/hip_runtime.h>

#define NNODES 8000
#define MPAD   8192          // 32 * 256 (for the 256x256 GEMM1 tile)
#define NEDGES 40000
#define ETOT   (NEDGES + NNODES)   // 48000 with self loops
#define DIN    1024
#define NH     3
#define CH     1024
#define HC     (NH * CH)           // 3072
#define NTOT   (2 * HC)            // 6144 fused xl||xr
#define NCLS   460
#define NCLS_P 512
#define NEG    0.2f

typedef _Float16 h8 __attribute__((ext_vector_type(8)));
typedef _Float16 h4v __attribute__((ext_vector_type(4)));
typedef float    f4 __attribute__((ext_vector_type(4)));

// async global->LDS, 16B per lane; dest = wave-uniform base + lane*16 (m104)
#define GLOAD16(g, l) \
    __builtin_amdgcn_global_load_lds((const __attribute__((address_space(1))) void*)(g), \
                                     (__attribute__((address_space(3))) void*)(l), 16, 0, 0)

// ---------- fp32 -> fp16 convert with row padding ----------
__global__ __launch_bounds__(256)
void fp16_pad_convert(const float* __restrict__ in, _Float16* __restrict__ out,
                      int rows_in, int rows_out, int cols)
{
    size_t i4 = (size_t)blockIdx.x * 256 + threadIdx.x;
    size_t tot = ((size_t)rows_out * cols) >> 2;
    if (i4 >= tot) return;
    size_t e = i4 << 2;
    int row = (int)(e / cols);
    float vx = 0.f, vy = 0.f, vz = 0.f, vw = 0.f;
    if (row < rows_in) {
        float4 v = *(const float4*)(in + e);
        vx = v.x; vy = v.y; vz = v.z; vw = v.w;
    }
    h4v o = { (_Float16)vx, (_Float16)vy, (_Float16)vz, (_Float16)vw };
    *(h4v*)(out + e) = o;
}

// ---------- W[K][Ncols] fp32 -> Wt[rowOff+n][K] fp16 (zero for n >= Ncols) ----------
__global__ __launch_bounds__(256)
void transpose_to_fp16(const float* __restrict__ W, _Float16* __restrict__ Wt,
                       int K, int Ncols, int rowOff)
{
    __shared__ float tile[32][33];
    int n0 = blockIdx.x * 32, k0 = blockIdx.y * 32;
    int tx = threadIdx.x, ty = threadIdx.y;   // block (32,8)
    #pragma unroll
    for (int i = 0; i < 4; ++i) {
        int k = k0 + ty + i * 8;
        int n = n0 + tx;
        tile[ty + i * 8][tx] = (n < Ncols) ? W[(size_t)k * Ncols + n] : 0.f;
    }
    __syncthreads();
    #pragma unroll
    for (int i = 0; i < 4; ++i) {
        int n = n0 + ty + i * 8;
        int k = k0 + tx;
        Wt[(size_t)(rowOff + n) * K + k] = (_Float16)tile[tx][ty + i * 8];
    }
}

// ---------- pack biases + att->fp16 ----------
__global__ __launch_bounds__(256)
void bias_pack(const float* __restrict__ bl, const float* __restrict__ br,
               const float* __restrict__ bf, const float* __restrict__ att,
               float* __restrict__ b1, float* __restrict__ b2, _Float16* __restrict__ atth)
{
    int i = blockIdx.x * 256 + threadIdx.x;
    if (i < HC) { b1[i] = bl[i]; b1[HC + i] = br[i]; atth[i] = (_Float16)att[i]; }
    if (i < NCLS_P) b2[i] = (i < NCLS) ? bf[i] : 0.f;
}

// ---------- CSR build ----------
__global__ __launch_bounds__(256)
void csr_count(const int* __restrict__ ei, int* __restrict__ cnt)
{
    int e = blockIdx.x * 256 + threadIdx.x;
    if (e >= ETOT) return;
    int dst = (e < NEDGES) ? ei[2 * e + 1] : (e - NEDGES);
    atomicAdd(&cnt[dst], 1);
}

__global__ __launch_bounds__(1024)
void csr_scan(const int* __restrict__ cnt, int* __restrict__ rofs)
{
    __shared__ int s[1024];
    int t = threadIdx.x;
    int base = t * 8;
    int local[8];
    int sum = 0;
    #pragma unroll
    for (int i = 0; i < 8; ++i) {
        local[i] = sum;
        sum += (base + i < NNODES) ? cnt[base + i] : 0;
    }
    s[t] = sum;
    __syncthreads();
    for (int off = 1; off < 1024; off <<= 1) {
        int v = (t >= off) ? s[t - off] : 0;
        __syncthreads();
        if (t >= off) s[t] += v;
        __syncthreads();
    }
    int pre = (t > 0) ? s[t - 1] : 0;
    #pragma unroll
    for (int i = 0; i < 8; ++i)
        if (base + i < NNODES) rofs[base + i] = pre + local[i];
}

__global__ __launch_bounds__(256)
void csr_fill(const int* __restrict__ ei, const int* __restrict__ rofs,
              int* __restrict__ cursor, int* __restrict__ csr_src)
{
    int e = blockIdx.x * 256 + threadIdx.x;
    if (e >= ETOT) return;
    int src, dst;
    if (e < NEDGES) { src = ei[2 * e]; dst = ei[2 * e + 1]; }
    else            { src = dst = e - NEDGES; }
    int pos = rofs[dst] + atomicAdd(&cursor[dst], 1);
    csr_src[pos] = src;
}

// ---------- 256x256 8-phase fp16 MFMA GEMM (T2+T3+T4+T5) ----------
// T2: LDS linear for gload_lds; 16B-chunk XOR swizzle applied on the GLOBAL
// source during staging and on the ds_read address (chunk ^= row&7) — the
// same involution both sides (rule #21), bijective per row.
__global__ __launch_bounds__(512, 2)
void gemm256_f16(const _Float16* __restrict__ A, const _Float16* __restrict__ Bt,
                 const float* __restrict__ biasN, _Float16* __restrict__ C16,
                 int N, int K)
{
    __shared__ __align__(16) _Float16 lds[65536];   // [buf]{A[256][64] | B[256][64]}

    // XCD swizzle (nwg % 8 == 0)
    int nwg = gridDim.x;
    int orig = blockIdx.x;
    int cpx = nwg >> 3;
    int wg = (orig & 7) * cpx + (orig >> 3);
    int nbx = N >> 8;
    int bm = wg / nbx, bn = wg - bm * nbx;
    int m0 = bm << 8, n0 = bn << 8;

    const int t = threadIdx.x;
    const int lane = t & 63;
    const int w = t >> 6;          // wave 0..7
    const int wm = w >> 2;         // 0..1  (M half)
    const int wn = w & 3;          // 0..3  (N quarter)

    // staging: each gload = 1KB segment = 8 rows x 64 fp16; lane l -> (row l>>3,
    // chunk l&7). Pre-swizzled source chunk = (l&7) ^ (l>>3)  [row&7 == l>>3]
    const int sRow   = lane >> 3;
    const int sColSw = (((lane & 7) ^ sRow) << 3);   // fp16 units
    const int seg0   = w << 1;                        // wave's first segment

    const int l15 = lane & 15;

    f4 acc[8][4];
    f4 zero = { 0.f, 0.f, 0.f, 0.f };
    #pragma unroll
    for (int i = 0; i < 8; ++i)
        #pragma unroll
        for (int j = 0; j < 4; ++j) acc[i][j] = zero;

    auto STAGE_A = [&](int kt, int h, int b) {
        const _Float16* src = A + (size_t)(m0 + h * 128 + seg0 * 8 + sRow) * K + kt * 64 + sColSw;
        int dst = b * 32768 + h * 8192 + seg0 * 512;
        GLOAD16(src, &lds[dst]);
        GLOAD16(src + (size_t)8 * K, &lds[dst + 512]);
    };
    auto STAGE_B = [&](int kt, int h, int b) {
        const _Float16* src = Bt + (size_t)(n0 + h * 128 + seg0 * 8 + sRow) * K + kt * 64 + sColSw;
        int dst = b * 32768 + 16384 + h * 8192 + seg0 * 512;
        GLOAD16(src, &lds[dst]);
        GLOAD16(src + (size_t)8 * K, &lds[dst + 512]);
    };

    h8 bfr[4][2];
    const int aBase = wm * 128 + l15;
    const int bBase = wn * 64 + l15;

// swizzled within-row fp16 offset for k-chunk (ks2*4 + lane>>4) of row with row&7==l15&7
#define SWC(ks2) (((((ks2) * 4 + (lane >> 4)) ^ (l15 & 7)) << 3))
#define DS_A(fi, ks2, q, b) (*(const h8*)&lds[(b)*32768 + (aBase + (q)*32 + (fi)*16)*64 + SWC(ks2)])
#define DS_B(nf, ks2, b)    (*(const h8*)&lds[(b)*32768 + 16384 + (bBase + (nf)*16)*64 + SWC(ks2)])

#define PHASE(b, q, STAGE_STMT, VMEND)                                                            \
    {                                                                                             \
        h8 a00 = DS_A(0, 0, q, b), a01 = DS_A(0, 1, q, b);                                        \
        h8 a10 = DS_A(1, 0, q, b), a11 = DS_A(1, 1, q, b);                                        \
        if ((q) == 0) {                                                                           \
            _Pragma("unroll")                                                                     \
            for (int nf = 0; nf < 4; ++nf) {                                                      \
                bfr[nf][0] = DS_B(nf, 0, b);                                                      \
                bfr[nf][1] = DS_B(nf, 1, b);                                                      \
            }                                                                                     \
        }                                                                                         \
        STAGE_STMT;                                                                               \
        __builtin_amdgcn_s_barrier();                                                             \
        asm volatile("s_waitcnt lgkmcnt(0)" ::: "memory");                                        \
        __builtin_amdgcn_sched_barrier(0);                                                        \
        __builtin_amdgcn_s_setprio(1);                                                            \
        _Pragma("unroll")                                                                         \
        for (int nf = 0; nf < 4; ++nf) {                                                          \
            acc[(q)*2+0][nf] = __builtin_amdgcn_mfma_f32_16x16x32_f16(a00, bfr[nf][0], acc[(q)*2+0][nf], 0, 0, 0); \
            acc[(q)*2+0][nf] = __builtin_amdgcn_mfma_f32_16x16x32_f16(a01, bfr[nf][1], acc[(q)*2+0][nf], 0, 0, 0); \
            acc[(q)*2+1][nf] = __builtin_amdgcn_mfma_f32_16x16x32_f16(a10, bfr[nf][0], acc[(q)*2+1][nf], 0, 0, 0); \
            acc[(q)*2+1][nf] = __builtin_amdgcn_mfma_f32_16x16x32_f16(a11, bfr[nf][1], acc[(q)*2+1][nf], 0, 0, 0); \
        }                                                                                         \
        __builtin_amdgcn_s_setprio(0);                                                            \
        if (VMEND) asm volatile("s_waitcnt vmcnt(4)" ::: "memory");                               \
        __builtin_amdgcn_s_barrier();                                                             \
    }

    // prologue: kt0 fully + kt1's B halves (A(kt1) staged at p0/p1 of iter 0)
    STAGE_A(0, 0, 0); STAGE_A(0, 1, 0);
    STAGE_B(0, 0, 0); STAGE_B(0, 1, 0);
    STAGE_B(1, 0, 1); STAGE_B(1, 1, 1);
    asm volatile("s_waitcnt vmcnt(4)" ::: "memory");   // kt0's 8 loads landed
    __builtin_amdgcn_s_barrier();

    const int NKT = K >> 6;    // 16 K-tiles
    for (int kt = 0; kt < NKT; kt += 2) {
        // phases 0-3: compute kt (buf0)
        PHASE(0, 0, STAGE_A(kt + 1, 0, 1), false);
        PHASE(0, 1, STAGE_A(kt + 1, 1, 1), false);
        PHASE(0, 2, STAGE_B(kt + 2, 0, 0), false);
        PHASE(0, 3, STAGE_B(kt + 2, 1, 0), true);    // vmcnt(4): A(kt+1) landed
        // phases 4-7: compute kt+1 (buf1)
        PHASE(1, 0, STAGE_A(kt + 2, 0, 0), false);
        PHASE(1, 1, STAGE_A(kt + 2, 1, 0), false);
        PHASE(1, 2, STAGE_B(kt + 3, 0, 1), false);
        PHASE(1, 3, STAGE_B(kt + 3, 1, 1), true);    // vmcnt(4): A/B(kt+2) landed
    }
    // (stages past NKT read harmless in-workspace bytes into dead buffers)

#undef PHASE
#undef DS_A
#undef DS_B
#undef SWC

    // epilogue: C/D layout col=lane&15, row=(lane>>4)*4+reg (m89-verified)
    #pragma unroll
    for (int mf = 0; mf < 8; ++mf) {
        int row0 = m0 + wm * 128 + mf * 16 + ((lane >> 4) << 2);
        #pragma unroll
        for (int nf = 0; nf < 4; ++nf) {
            int col = n0 + wn * 64 + nf * 16 + l15;
            float bb = biasN[col];
            #pragma unroll
            for (int rg = 0; rg < 4; ++rg)
                C16[(size_t)(row0 + rg) * N + col] = (_Float16)(acc[mf][nf][rg] + bb);
        }
    }
}

// ---------- 128x128 fp16 MFMA GEMM (kept for GEMM2's narrow N) ----------
__global__ __launch_bounds__(256, 4)
void gemm_f16(const _Float16* __restrict__ A, const _Float16* __restrict__ Bt,
              const float* __restrict__ biasN,
              float* __restrict__ C32, _Float16* __restrict__ C16,
              int N, int K)
{
    __shared__ __align__(16) _Float16 sA[128 * 32];
    __shared__ __align__(16) _Float16 sB[128 * 32];

    int nwg = gridDim.x;
    int orig = blockIdx.x;
    int q = nwg >> 3, r = nwg & 7;
    int xcd = orig & 7, idx = orig >> 3;
    int wg = (xcd < r ? xcd * (q + 1) : r * (q + 1) + (xcd - r) * q) + idx;
    int nbx = N >> 7;
    int bm = wg / nbx, bn = wg - bm * nbx;
    int m0 = bm << 7, n0 = bn << 7;

    const int t = threadIdx.x;
    const int lane = t & 63, w = t >> 6;
    const int wr = (w >> 1) << 6, wc = (w & 1) << 6;

    f4 acc[4][4];
    f4 zero = { 0.f, 0.f, 0.f, 0.f };
    #pragma unroll
    for (int i = 0; i < 4; ++i)
        #pragma unroll
        for (int j = 0; j < 4; ++j) acc[i][j] = zero;

    const int lr = lane >> 2, lk = lane & 3;
    const _Float16* gA = A  + (size_t)(m0 + w * 16 + lr) * K + lk * 8;
    const _Float16* gB = Bt + (size_t)(n0 + w * 16 + lr) * K + lk * 8;
    _Float16* lA0 = &sA[w * 512];
    _Float16* lA1 = &sA[2048 + w * 512];
    _Float16* lB0 = &sB[w * 512];
    _Float16* lB1 = &sB[2048 + w * 512];
    const size_t seg = (size_t)64 * K;

    const int nk = K >> 5;
    for (int s = 0; s < nk; ++s) {
        const int ko = s << 5;
        GLOAD16(gA + ko,       lA0);
        GLOAD16(gA + seg + ko, lA1);
        GLOAD16(gB + ko,       lB0);
        GLOAD16(gB + seg + ko, lB1);
        __syncthreads();
        const int ks = lane >> 4;
        h8 bh[4];
        #pragma unroll
        for (int nj = 0; nj < 4; ++nj)
            bh[nj] = *(const h8*)&sB[(wc + nj * 16 + (lane & 15)) * 32 + ks * 8];
        #pragma unroll
        for (int mi = 0; mi < 4; ++mi) {
            h8 ah = *(const h8*)&sA[(wr + mi * 16 + (lane & 15)) * 32 + ks * 8];
            #pragma unroll
            for (int nj = 0; nj < 4; ++nj)
                acc[mi][nj] = __builtin_amdgcn_mfma_f32_16x16x32_f16(ah, bh[nj], acc[mi][nj], 0, 0, 0);
        }
        __syncthreads();
    }

    #pragma unroll
    for (int mi = 0; mi < 4; ++mi) {
        #pragma unroll
        for (int nj = 0; nj < 4; ++nj) {
            int col  = n0 + wc + nj * 16 + (lane & 15);
            int rowb = m0 + wr + mi * 16 + ((lane >> 4) << 2);
            float b = biasN[col];
            #pragma unroll
            for (int rg = 0; rg < 4; ++rg) {
                float v = acc[mi][nj][rg] + b;
                size_t off = (size_t)(rowb + rg) * N + col;
                if (C32) C32[off] = v;
                else     C16[off] = (_Float16)v;
            }
        }
    }
}

// ---------- fused edge path v3: block = 3 waves = one dst, wave = one head ----------
// lane l owns channels [l*8, +8) and [512+l*8, +8) of its head's 1024 slice.
// Per edge: 2 h8 loads (next edge prefetched into named regs before the reduce
// chain); score via shfl_xor butterfly; online softmax in registers.
// ONE barrier per block: heads combine via 12KB LDS, +bias, fp16 store.
__global__ __launch_bounds__(192)
void edge_fused3(const _Float16* __restrict__ xlr, const int* __restrict__ rofs,
                 const int* __restrict__ cnt, const int* __restrict__ csr_src,
                 const _Float16* __restrict__ atth, const float* __restrict__ bias,
                 _Float16* __restrict__ o2h)
{
    __shared__ float comb[3 * CH];   // 12 KB

    const int dst = blockIdx.x;
    const int h   = threadIdx.x >> 6;    // wave = head
    const int l   = threadIdx.x & 63;
    const int cb0 = l << 3, cb1 = 512 + (l << 3);

    const _Float16* pr = xlr + (size_t)dst * NTOT + HC + h * CH;
    h8 xr0 = *(const h8*)(pr + cb0);
    h8 xr1 = *(const h8*)(pr + cb1);
    h8 at0 = *(const h8*)(atth + h * CH + cb0);
    h8 at1 = *(const h8*)(atth + h * CH + cb1);

    const int beg = rofs[dst];
    const int num = cnt[dst];

    float m = -3.4e38f, d = 0.f;
    float a0[8] = {}, a1[8] = {};

    // prefetch edge 0
    int src0 = csr_src[beg];
    const _Float16* p0 = xlr + (size_t)src0 * NTOT + h * CH;
    h8 nx0 = *(const h8*)(p0 + cb0);
    h8 nx1 = *(const h8*)(p0 + cb1);

    for (int i = 0; i < num; ++i) {
        h8 xv0 = nx0, xv1 = nx1;
        if (i + 1 < num) {                      // issue next loads before the chain
            int s2 = csr_src[beg + i + 1];
            const _Float16* p2 = xlr + (size_t)s2 * NTOT + h * CH;
            nx0 = *(const h8*)(p2 + cb0);
            nx1 = *(const h8*)(p2 + cb1);
        }
        float s = 0.f;
        #pragma unroll
        for (int j = 0; j < 8; ++j) {
            float z0 = (float)xv0[j] + (float)xr0[j];
            z0 = z0 > 0.f ? z0 : NEG * z0;
            s = fmaf((float)at0[j], z0, s);
            float z1 = (float)xv1[j] + (float)xr1[j];
            z1 = z1 > 0.f ? z1 : NEG * z1;
            s = fmaf((float)at1[j], z1, s);
        }
        #pragma unroll
        for (int off = 32; off > 0; off >>= 1) s += __shfl_xor(s, off);
        float nm = fmaxf(m, s);
        float rs = __expf(m - nm);              // first iter: exp(-big)=0
        float wt = __expf(s - nm);
        d = d * rs + wt;
        #pragma unroll
        for (int j = 0; j < 8; ++j) {
            a0[j] = fmaf(wt, (float)xv0[j], a0[j] * rs);
            a1[j] = fmaf(wt, (float)xv1[j], a1[j] * rs);
        }
        m = nm;
    }

    float inv = 1.f / (d + 1e-16f) * (1.f / 3.f);
    #pragma unroll
    for (int j = 0; j < 8; ++j) {
        comb[h * CH + cb0 + j] = a0[j] * inv;
        comb[h * CH + cb1 + j] = a1[j] * inv;
    }
    __syncthreads();

    if (threadIdx.x < 128) {
        int c = threadIdx.x << 3;
        h8 o;
        #pragma unroll
        for (int j = 0; j < 8; ++j) {
            float v = comb[c + j] + comb[CH + c + j] + comb[2 * CH + c + j] + bias[c + j];
            o[j] = (_Float16)v;
        }
        *(h8*)(o2h + (size_t)dst * CH + c) = o;
    }
}

// ---------- row softmax over 460 classes, ld 512 ----------
__global__ __launch_bounds__(64)
void row_softmax(const float* __restrict__ logits, float* __restrict__ out)
{
    const int r = blockIdx.x;
    const int lane = threadIdx.x;
    const float* row = logits + (size_t)r * NCLS_P;
    float v[8];
    float mx = -3.4e38f;
    #pragma unroll
    for (int i = 0; i < 8; ++i) {
        int c = lane + i * 64;
        v[i] = (c < NCLS) ? row[c] : -3.4e38f;
        mx = fmaxf(mx, v[i]);
    }
    #pragma unroll
    for (int off = 32; off > 0; off >>= 1) mx = fmaxf(mx, __shfl_xor(mx, off));
    float s = 0.f;
    #pragma unroll
    for (int i = 0; i < 8; ++i) {
        int c = lane + i * 64;
        float ev = (c < NCLS) ? expf(v[i] - mx) : 0.f;
        v[i] = ev;
        s += ev;
    }
    #pragma unroll
    for (int off = 32; off > 0; off >>= 1) s += __shfl_xor(s, off);
    float inv = 1.f / s;
    #pragma unroll
    for (int i = 0; i < 8; ++i) {
        int c = lane + i * 64;
        if (c < NCLS) out[(size_t)r * NCLS + c] = v[i] * inv;
    }
}

extern "C" void kernel_launch(void* const* d_in, const int* in_sizes, int n_in,
                              void* d_out, int out_size, void* d_ws, size_t ws_size,
                              hipStream_t stream)
{
    (void)in_sizes; (void)n_in; (void)out_size; (void)ws_size;

    const float* x    = (const float*)d_in[0];
    const int*   ei   = (const int*)  d_in[1];
    const float* Wl   = (const float*)d_in[2];
    const float* bl   = (const float*)d_in[3];
    const float* Wr   = (const float*)d_in[4];
    const float* br   = (const float*)d_in[5];
    const float* att  = (const float*)d_in[6];
    const float* bias = (const float*)d_in[7];
    const float* Wf   = (const float*)d_in[8];
    const float* bf   = (const float*)d_in[9];

    char* base = (char*)d_ws;
    _Float16* xh      = (_Float16*)(base);                      // [8192][1024]   16,777,216
    _Float16* BtW     = (_Float16*)(base + 16777216);           // [6144][1024]   12,582,912
    _Float16* Wft     = (_Float16*)(base + 29360128);           // [512][1024]     1,048,576
    float*    biasC1  = (float*)   (base + 30408704);           // [6144]             24,576
    float*    biasC2  = (float*)   (base + 30433280);           // [512]               2,048
    _Float16* atth    = (_Float16*)(base + 30435328);           // [3072]              6,144
    int*      cnt     = (int*)     (base + 30441472);           // [8000]             32,000
    int*      cursor  = (int*)     (base + 30473472);           // [8000]             32,000
    int*      rofs    = (int*)     (base + 30505472);           // [8000]             32,000
    int*      csr_src = (int*)     (base + 30537472);           // [48000]           192,000
    _Float16* o2h     = (_Float16*)(base + 30729472);           // [8192][1024]   16,777,216
    float*    logits  = (float*)   (base + 47506688);           // [8192][512]    16,777,216
    _Float16* xlr     = (_Float16*)(base + 64283904);           // [8192][6144]  100,663,296

    // zero cnt | cursor (contiguous) and o2h pad rows (8000..8191)
    hipMemsetAsync(cnt, 0, 64000, stream);
    hipMemsetAsync(o2h + (size_t)NNODES * CH, 0, (size_t)(MPAD - NNODES) * CH * 2, stream);

    fp16_pad_convert<<<(MPAD * DIN / 4 + 255) / 256, 256, 0, stream>>>(
        x, xh, NNODES, MPAD, DIN);

    transpose_to_fp16<<<dim3(HC / 32, DIN / 32), dim3(32, 8), 0, stream>>>(Wl, BtW, DIN, HC, 0);
    transpose_to_fp16<<<dim3(HC / 32, DIN / 32), dim3(32, 8), 0, stream>>>(Wr, BtW, DIN, HC, HC);
    transpose_to_fp16<<<dim3(NCLS_P / 32, DIN / 32), dim3(32, 8), 0, stream>>>(Wf, Wft, DIN, NCLS, 0);

    bias_pack<<<(HC + 255) / 256, 256, 0, stream>>>(bl, br, bf, att, biasC1, biasC2, atth);

    // CSR build (src lists per dst, self-loops included)
    csr_count<<<(ETOT + 255) / 256, 256, 0, stream>>>(ei, cnt);
    csr_scan<<<1, 1024, 0, stream>>>(cnt, rofs);
    csr_fill<<<(ETOT + 255) / 256, 256, 0, stream>>>(ei, rofs, cursor, csr_src);

    // GEMM1 fused (256^2 8-phase + T2 swizzle): xlr[8192][6144] fp16
    gemm256_f16<<<(MPAD / 256) * (NTOT / 256), 512, 0, stream>>>(
        xh, BtW, biasC1, xlr, NTOT, DIN);

    // fused edge path: 3-wave block per dst, wave-per-head, pipelined gathers
    edge_fused3<<<NNODES, 192, 0, stream>>>(xlr, rofs, cnt, csr_src, atth, bias, o2h);

    // GEMM2: logits[8192][512] fp32
    gemm_f16<<<(NCLS_P / 128) * (MPAD / 128), 256, 0, stream>>>(
        o2h, Wft, biasC2, logits, nullptr, NCLS_P, DIN);

    row_softmax<<<NNODES, 64, 0, stream>>>(logits, (float*)d_out);
}